// Round 1
// baseline (504.328 us; speedup 1.0000x reference)
//
#include <hip/hip_runtime.h>

#define B_ 8
#define C_ 256
#define N_ 4096
#define CK 32
#define CG 128
#define M_ 1024

// ---------------- theta projection: theta[b,o,n] = sum_c w_theta[o,c] x[b,c,n]
__global__ __launch_bounds__(256) void theta_kernel(const float* __restrict__ x,
                                                    const float* __restrict__ wt,
                                                    float* __restrict__ theta) {
  __shared__ float w_s[CK * C_];  // 32 KB
  int tid = threadIdx.x;
  int b = blockIdx.y, n0 = blockIdx.x * 64;
#pragma unroll
  for (int k = 0; k < 32; ++k) w_s[tid + k * 256] = wt[tid + k * 256];
  __syncthreads();
  int nl = tid & 63, oq = tid >> 6;  // oq in 0..3, wave-uniform
  int n = n0 + nl;
  float acc[8] = {0.f, 0.f, 0.f, 0.f, 0.f, 0.f, 0.f, 0.f};
  const float* xp = x + (size_t)b * C_ * N_ + n;
  for (int c = 0; c < C_; ++c) {
    float xv = xp[(size_t)c * N_];
#pragma unroll
    for (int k = 0; k < 8; ++k) acc[k] += w_s[(oq * 8 + k) * C_ + c] * xv;
  }
#pragma unroll
  for (int k = 0; k < 8; ++k)
    theta[((size_t)b * CK + oq * 8 + k) * N_ + n] = acc[k];
}

// ---------------- pooled projections: conv at 4 pixels then 2x2 max pool
// grp 0 -> phi (32 out), grp 1..4 -> g rows (grp-1)*32..
__global__ __launch_bounds__(256) void pool_kernel(const float* __restrict__ x,
                                                   const float* __restrict__ wphi,
                                                   const float* __restrict__ wg,
                                                   float* __restrict__ phi,
                                                   float* __restrict__ g) {
  __shared__ float w_s[32 * C_];  // 32 KB
  int tid = threadIdx.x;
  int mt = blockIdx.x, b = blockIdx.y, grp = blockIdx.z;
  const float* wsrc = (grp == 0) ? wphi : (wg + (size_t)(grp - 1) * 32 * C_);
#pragma unroll
  for (int k = 0; k < 32; ++k) w_s[tid + k * 256] = wsrc[tid + k * 256];
  __syncthreads();
  int ml = tid >> 2, p = tid & 3;  // 4 consecutive lanes = 4 pixels of one pooled m
  int m = mt * 64 + ml;
  int ph = m >> 5, pw = m & 31;
  int py = 2 * ph + (p >> 1), px = 2 * pw + (p & 1);
  const float* xp = x + (size_t)b * C_ * N_ + py * 64 + px;
  float acc[32];
#pragma unroll
  for (int o = 0; o < 32; ++o) acc[o] = 0.f;
  for (int c = 0; c < C_; ++c) {
    float xv = xp[(size_t)c * N_];
#pragma unroll
    for (int o = 0; o < 32; ++o) acc[o] += w_s[o * C_ + c] * xv;
  }
  float* dst = (grp == 0) ? (phi + (size_t)b * CK * M_)
                          : (g + ((size_t)b * CG + (grp - 1) * 32) * M_);
#pragma unroll
  for (int o = 0; o < 32; ++o) {
    float v = acc[o];
    v = fmaxf(v, __shfl_xor(v, 1));
    v = fmaxf(v, __shfl_xor(v, 2));
    if (p == 0) dst[(size_t)o * M_ + m] = v;
  }
}

// ---------------- fused flash attention: logits -> online softmax -> PV
// block: b, 64 queries. m tiled by 64 (16 tiles).
__global__ __launch_bounds__(256) void attn_kernel(const float* __restrict__ theta,
                                                   const float* __restrict__ phi,
                                                   const float* __restrict__ g,
                                                   float* __restrict__ o_mid) {
  __shared__ __align__(16) float ph_s[64 * 36];   // [m][c], rowstride 36 -> QK conflict-free
  __shared__ __align__(16) float g_s[64 * 132];   // [m][c], rowstride 132
  __shared__ __align__(16) float p_s[64 * 68];    // [m][n], rowstride 68 (also theta staging)
  __shared__ float f_s[64];
  int tid = threadIdx.x;
  int b = blockIdx.y, n0 = blockIdx.x * 64;

  // stage theta tile through p_s, then hoist to registers (reused all 16 tiles)
#pragma unroll
  for (int k = 0; k < 8; ++k) {
    int e = tid + k * 256, c = e >> 6, j = e & 63;
    p_s[e] = theta[((size_t)b * CK + c) * N_ + n0 + j];
  }
  __syncthreads();
  int nl = tid >> 2, t = tid & 3;  // QK mapping: 4 lanes per query row
  float th[32];
#pragma unroll
  for (int c = 0; c < 32; ++c) th[c] = p_s[c * 64 + nl];

  int q = tid & 15, r = tid >> 4;  // PV mapping: c in {4q..4q+3, 64+4q..}, n = 4r..4r+3
  float acc0[4][4], acc1[4][4];
#pragma unroll
  for (int k = 0; k < 4; ++k)
#pragma unroll
    for (int j = 0; j < 4; ++j) { acc0[k][j] = 0.f; acc1[k][j] = 0.f; }
  float Mx = -1e30f, S = 0.f;

  for (int mt = 0; mt < 16; ++mt) {
    int m0 = mt * 64;
    __syncthreads();  // protect LDS from previous-iteration readers (+theta hoist)
#pragma unroll
    for (int k = 0; k < 8; ++k) {
      int e = tid + k * 256, c = e >> 6, j = e & 63;
      ph_s[j * 36 + c] = phi[((size_t)b * CK + c) * M_ + m0 + j];
    }
#pragma unroll
    for (int k = 0; k < 32; ++k) {
      int e = tid + k * 256, c = e >> 6, j = e & 63;
      g_s[j * 132 + c] = g[((size_t)b * CG + c) * M_ + m0 + j];
    }
    __syncthreads();

    // QK^T: thread (nl, t) computes m = 4i+t
    float l[16];
#pragma unroll
    for (int i = 0; i < 16; ++i) {
      int m = 4 * i + t;
      const float* pm = &ph_s[m * 36];
      float s = 0.f;
#pragma unroll
      for (int cc = 0; cc < 8; ++cc) {
        float4 pv = *(const float4*)&pm[cc * 4];
        s += th[cc * 4 + 0] * pv.x + th[cc * 4 + 1] * pv.y +
             th[cc * 4 + 2] * pv.z + th[cc * 4 + 3] * pv.w;
      }
      l[i] = s;
    }
    // online softmax over the 4 t-lanes of each query row
    float tm = l[0];
#pragma unroll
    for (int i = 1; i < 16; ++i) tm = fmaxf(tm, l[i]);
    tm = fmaxf(tm, __shfl_xor(tm, 1));
    tm = fmaxf(tm, __shfl_xor(tm, 2));
    float Mn = fmaxf(Mx, tm);
    float f = __expf(Mx - Mn);  // first tile: exp(-1e30) = 0
    float ps = 0.f;
#pragma unroll
    for (int i = 0; i < 16; ++i) {
      float pv = __expf(l[i] - Mn);
      ps += pv;
      p_s[(4 * i + t) * 68 + nl] = pv;
    }
    ps += __shfl_xor(ps, 1);
    ps += __shfl_xor(ps, 2);
    S = S * f + ps;
    Mx = Mn;
    if (t == 0) f_s[nl] = f;
    __syncthreads();

    // PV: rescale then accumulate this tile
    float fr[4];
#pragma unroll
    for (int j = 0; j < 4; ++j) fr[j] = f_s[r * 4 + j];
#pragma unroll
    for (int k = 0; k < 4; ++k)
#pragma unroll
      for (int j = 0; j < 4; ++j) { acc0[k][j] *= fr[j]; acc1[k][j] *= fr[j]; }
    for (int m = 0; m < 64; ++m) {
      float4 ga = *(const float4*)&g_s[m * 132 + q * 4];
      float4 gb = *(const float4*)&g_s[m * 132 + 64 + q * 4];
      float4 pp = *(const float4*)&p_s[m * 68 + r * 4];
      const float* gaf = (const float*)&ga;
      const float* gbf = (const float*)&gb;
      const float* ppf = (const float*)&pp;
#pragma unroll
      for (int k = 0; k < 4; ++k)
#pragma unroll
        for (int j = 0; j < 4; ++j) {
          acc0[k][j] += gaf[k] * ppf[j];
          acc1[k][j] += gbf[k] * ppf[j];
        }
    }
  }
  __syncthreads();
  if (t == 0) f_s[nl] = S;  // reuse f_s for the final denominators
  __syncthreads();
  float Sr[4];
#pragma unroll
  for (int j = 0; j < 4; ++j) Sr[j] = 1.f / f_s[r * 4 + j];
#pragma unroll
  for (int k = 0; k < 4; ++k)
#pragma unroll
    for (int j = 0; j < 4; ++j) {
      o_mid[((size_t)b * CG + 4 * q + k) * N_ + n0 + r * 4 + j] = acc0[k][j] * Sr[j];
      o_mid[((size_t)b * CG + 64 + 4 * q + k) * N_ + n0 + r * 4 + j] = acc1[k][j] * Sr[j];
    }
}

// ---------------- out projection + residual: out = gamma * (w_o @ o_mid) + x
__global__ __launch_bounds__(512) void outproj_kernel(const float* __restrict__ o_mid,
                                                      const float* __restrict__ wo,
                                                      const float* __restrict__ x,
                                                      const float* __restrict__ gamma,
                                                      float* __restrict__ out) {
  __shared__ float w_s[128 * CG];  // 64 KB: half of w_o (z-split)
  int tid = threadIdx.x;
  int b = blockIdx.y, n0 = blockIdx.x * 64, z = blockIdx.z;
#pragma unroll
  for (int k = 0; k < 32; ++k)
    w_s[tid + k * 512] = wo[(size_t)z * 128 * CG + tid + k * 512];
  __syncthreads();
  int nl = tid & 63, oq = tid >> 6;  // oq in 0..7, wave-uniform
  int n = n0 + nl;
  float acc[16];
#pragma unroll
  for (int k = 0; k < 16; ++k) acc[k] = 0.f;
  const float* op = o_mid + (size_t)b * CG * N_ + n;
  for (int c = 0; c < CG; ++c) {
    float ov = op[(size_t)c * N_];
#pragma unroll
    for (int k = 0; k < 16; ++k) acc[k] += w_s[(oq * 16 + k) * CG + c] * ov;
  }
  float gm = gamma[0];
#pragma unroll
  for (int k = 0; k < 16; ++k) {
    int o = z * 128 + oq * 16 + k;
    size_t idx = ((size_t)b * C_ + o) * N_ + n;
    out[idx] = gm * acc[k] + x[idx];
  }
}

extern "C" void kernel_launch(void* const* d_in, const int* in_sizes, int n_in,
                              void* d_out, int out_size, void* d_ws, size_t ws_size,
                              hipStream_t stream) {
  const float* x = (const float*)d_in[0];
  const float* wt = (const float*)d_in[1];
  const float* wp = (const float*)d_in[2];
  const float* wg = (const float*)d_in[3];
  const float* wo = (const float*)d_in[4];
  const float* gamma = (const float*)d_in[5];
  float* out = (float*)d_out;

  float* theta = (float*)d_ws;                       // 8*32*4096   = 1,048,576 f
  float* phi = theta + (size_t)B_ * CK * N_;         // 8*32*1024   =   262,144 f
  float* g = phi + (size_t)B_ * CK * M_;             // 8*128*1024  = 1,048,576 f
  float* o_mid = g + (size_t)B_ * CG * M_;           // 8*128*4096  = 4,194,304 f

  theta_kernel<<<dim3(64, 8), 256, 0, stream>>>(x, wt, theta);
  pool_kernel<<<dim3(16, 8, 5), 256, 0, stream>>>(x, wp, wg, phi, g);
  attn_kernel<<<dim3(64, 8), 256, 0, stream>>>(theta, phi, g, o_mid);
  outproj_kernel<<<dim3(64, 8, 2), 512, 0, stream>>>(o_mid, wo, x, gamma, out);
}

// Round 2
// 215.763 us; speedup vs baseline: 2.3374x; 2.3374x over previous
//
#include <hip/hip_runtime.h>

#define B_ 8
#define C_ 256
#define N_ 4096
#define CK 32
#define CG 128
#define M_ 1024

typedef __attribute__((ext_vector_type(8))) short bf16x8;
typedef __attribute__((ext_vector_type(4))) float f32x4;
typedef __attribute__((ext_vector_type(2))) int i32x2;

__device__ __forceinline__ short f2bf(float f) {
  union { float f; unsigned u; } v; v.f = f;
  unsigned r = (v.u + 0x7FFF + ((v.u >> 16) & 1)) >> 16;  // RNE
  return (short)r;
}
__device__ __forceinline__ int packbf2(float a, float b) {
  return (f2bf(a) & 0xFFFF) | (f2bf(b) << 16);
}

// ---------------- theta projection: theta[b,o,n] = sum_c w_theta[o,c] x[b,c,n]
__global__ __launch_bounds__(256) void theta_kernel(const float* __restrict__ x,
                                                    const float* __restrict__ wt,
                                                    float* __restrict__ theta) {
  __shared__ float w_s[CK * C_];  // 32 KB
  int tid = threadIdx.x;
  int b = blockIdx.y, n0 = blockIdx.x * 64;
#pragma unroll
  for (int k = 0; k < 32; ++k) w_s[tid + k * 256] = wt[tid + k * 256];
  __syncthreads();
  int nl = tid & 63, oq = tid >> 6;  // oq in 0..3, wave-uniform
  int n = n0 + nl;
  float acc[8] = {0.f, 0.f, 0.f, 0.f, 0.f, 0.f, 0.f, 0.f};
  const float* xp = x + (size_t)b * C_ * N_ + n;
  for (int c = 0; c < C_; ++c) {
    float xv = xp[(size_t)c * N_];
#pragma unroll
    for (int k = 0; k < 8; ++k) acc[k] += w_s[(oq * 8 + k) * C_ + c] * xv;
  }
#pragma unroll
  for (int k = 0; k < 8; ++k)
    theta[((size_t)b * CK + oq * 8 + k) * N_ + n] = acc[k];
}

// ---------------- pooled projections: conv at 4 pixels then 2x2 max pool
__global__ __launch_bounds__(256) void pool_kernel(const float* __restrict__ x,
                                                   const float* __restrict__ wphi,
                                                   const float* __restrict__ wg,
                                                   float* __restrict__ phi,
                                                   float* __restrict__ g) {
  __shared__ float w_s[32 * C_];  // 32 KB
  int tid = threadIdx.x;
  int mt = blockIdx.x, b = blockIdx.y, grp = blockIdx.z;
  const float* wsrc = (grp == 0) ? wphi : (wg + (size_t)(grp - 1) * 32 * C_);
#pragma unroll
  for (int k = 0; k < 32; ++k) w_s[tid + k * 256] = wsrc[tid + k * 256];
  __syncthreads();
  int ml = tid >> 2, p = tid & 3;
  int m = mt * 64 + ml;
  int ph = m >> 5, pw = m & 31;
  int py = 2 * ph + (p >> 1), px = 2 * pw + (p & 1);
  const float* xp = x + (size_t)b * C_ * N_ + py * 64 + px;
  float acc[32];
#pragma unroll
  for (int o = 0; o < 32; ++o) acc[o] = 0.f;
  for (int c = 0; c < C_; ++c) {
    float xv = xp[(size_t)c * N_];
#pragma unroll
    for (int o = 0; o < 32; ++o) acc[o] += w_s[o * C_ + c] * xv;
  }
  float* dst = (grp == 0) ? (phi + (size_t)b * CK * M_)
                          : (g + ((size_t)b * CG + (grp - 1) * 32) * M_);
#pragma unroll
  for (int o = 0; o < 32; ++o) {
    float v = acc[o];
    v = fmaxf(v, __shfl_xor(v, 1));
    v = fmaxf(v, __shfl_xor(v, 2));
    if (p == 0) dst[(size_t)o * M_ + m] = v;
  }
}

// ---------------- fused flash attention with bf16 MFMA
// Swapped operands: QK^T tile computed as mfma(A=phi, B=theta) -> P^T[m][n],
// so each lane owns query-row n = lane&15. PV computed as mfma(A=V^T, B=P^T)
// -> O^T[c][n]. P re-distributed across lane-groups via per-wave LDS buffer.
// MFMA layouts (gfx950, m89-verified):
//   A[row][k]: lane l holds A[l&15][8*(l>>4)+j], j=0..7
//   B[k][col]: lane l holds B[8*(l>>4)+j][l&15]
//   D[row][col]: lane l, reg r holds D[4*(l>>4)+r][l&15]
__global__ __launch_bounds__(256) void attn_kernel(const float* __restrict__ theta,
                                                   const float* __restrict__ phi,
                                                   const float* __restrict__ g,
                                                   float* __restrict__ o_mid) {
  // phi_s[m][c]: stride 40 shorts (80B) -> b128 reads 16B-aligned, bank-even
  // g_s[c][m]:   stride 72 shorts (144B) -> b128 reads aligned, bank-even
  // p_s[w][q][m]: stride 72 shorts, per-wave private
  __shared__ __align__(16) short phi_s[64 * 40];   // 5120 B
  __shared__ __align__(16) short g_s[128 * 72];    // 18432 B
  __shared__ __align__(16) short p_s[4][16 * 72];  // 9216 B

  int tid = threadIdx.x;
  int lane = tid & 63, w = tid >> 6;
  int h = lane >> 4, q = lane & 15;
  int b = blockIdx.y, n0 = blockIdx.x * 64;

  // theta B-fragment (reused for all 16 m-tiles): B[k=c][col=n]
  bf16x8 qfrag;
  {
    int n = n0 + 16 * w + q;
#pragma unroll
    for (int j = 0; j < 8; ++j)
      qfrag[j] = f2bf(theta[((size_t)b * CK + 8 * h + j) * N_ + n]);
  }

  f32x4 Oacc[8];
#pragma unroll
  for (int ct = 0; ct < 8; ++ct) Oacc[ct] = (f32x4){0.f, 0.f, 0.f, 0.f};
  float Mx = -INFINITY, S = 0.f;
  const f32x4 zero4 = {0.f, 0.f, 0.f, 0.f};

  for (int mt16 = 0; mt16 < 16; ++mt16) {
    int m0 = mt16 * 64;
    __syncthreads();  // previous tile's readers done
    // stage phi tile: phi_s[m][c] = bf16(phi[b][c][m0+m]); paired over c
#pragma unroll
    for (int k = 0; k < 4; ++k) {
      int idx = k * 256 + tid;
      int m = idx & 63, cp = idx >> 6;  // cp in 0..15
      float f0 = phi[((size_t)b * CK + 2 * cp) * M_ + m0 + m];
      float f1 = phi[((size_t)b * CK + 2 * cp + 1) * M_ + m0 + m];
      *(int*)&phi_s[m * 40 + 2 * cp] = packbf2(f0, f1);
    }
    // stage g tile: g_s[c][m] = bf16(g[b][c][m0+m]); paired over m
#pragma unroll
    for (int k = 0; k < 16; ++k) {
      int idx = k * 256 + tid;
      int c = idx >> 5, mp = idx & 31;
      const float2 v = *(const float2*)&g[((size_t)b * CG + c) * M_ + m0 + 2 * mp];
      *(int*)&g_s[c * 72 + 2 * mp] = packbf2(v.x, v.y);
    }
    __syncthreads();

    // QK^T: P^T subtiles, A = phi_s rows m, B = qfrag
    f32x4 pt[4];
#pragma unroll
    for (int mt = 0; mt < 4; ++mt) {
      bf16x8 af = *(const bf16x8*)&phi_s[(16 * mt + q) * 40 + 8 * h];
      pt[mt] = __builtin_amdgcn_mfma_f32_16x16x32_bf16(af, qfrag, zero4, 0, 0, 0);
    }

    // online softmax over this tile's 64 m-values of row n=q
    float pm = pt[0][0];
#pragma unroll
    for (int mt = 0; mt < 4; ++mt)
#pragma unroll
      for (int r = 0; r < 4; ++r) pm = fmaxf(pm, pt[mt][r]);
    pm = fmaxf(pm, __shfl_xor(pm, 16));
    pm = fmaxf(pm, __shfl_xor(pm, 32));
    float Mn = fmaxf(Mx, pm);
    float fsc = __expf(Mx - Mn);
    float ps = 0.f;
#pragma unroll
    for (int mt = 0; mt < 4; ++mt) {
      float e0 = __expf(pt[mt][0] - Mn);
      float e1 = __expf(pt[mt][1] - Mn);
      float e2 = __expf(pt[mt][2] - Mn);
      float e3 = __expf(pt[mt][3] - Mn);
      ps += (e0 + e1) + (e2 + e3);
      i32x2 pk;
      pk[0] = packbf2(e0, e1);
      pk[1] = packbf2(e2, e3);
      // p_s[w][q][m], m = 16*mt + 4*h + r
      *(i32x2*)&p_s[w][q * 72 + 16 * mt + 4 * h] = pk;
    }
    ps += __shfl_xor(ps, 16);
    ps += __shfl_xor(ps, 32);
    S = S * fsc + ps;
    Mx = Mn;
#pragma unroll
    for (int ct = 0; ct < 8; ++ct) Oacc[ct] *= fsc;

    // PV: O^T += V^T * P^T ; A = g_s rows c, B = p_s rows n
#pragma unroll
    for (int kp = 0; kp < 2; ++kp) {
      bf16x8 pf = *(const bf16x8*)&p_s[w][q * 72 + 32 * kp + 8 * h];
#pragma unroll
      for (int ct = 0; ct < 8; ++ct) {
        bf16x8 vf = *(const bf16x8*)&g_s[(16 * ct + q) * 72 + 32 * kp + 8 * h];
        Oacc[ct] = __builtin_amdgcn_mfma_f32_16x16x32_bf16(vf, pf, Oacc[ct], 0, 0, 0);
      }
    }
  }

  // epilogue: O[c][n=q] / S  (all lanes hold S for their own row q)
  float rS = 1.f / S;
  int n = n0 + 16 * w + q;
#pragma unroll
  for (int ct = 0; ct < 8; ++ct)
#pragma unroll
    for (int r = 0; r < 4; ++r) {
      int c = 16 * ct + 4 * h + r;
      o_mid[((size_t)b * CG + c) * N_ + n] = Oacc[ct][r] * rS;
    }
}

// ---------------- out projection + residual: out = gamma * (w_o @ o_mid) + x
__global__ __launch_bounds__(512) void outproj_kernel(const float* __restrict__ o_mid,
                                                      const float* __restrict__ wo,
                                                      const float* __restrict__ x,
                                                      const float* __restrict__ gamma,
                                                      float* __restrict__ out) {
  __shared__ float w_s[128 * CG];  // 64 KB: half of w_o (z-split)
  int tid = threadIdx.x;
  int b = blockIdx.y, n0 = blockIdx.x * 64, z = blockIdx.z;
#pragma unroll
  for (int k = 0; k < 32; ++k)
    w_s[tid + k * 512] = wo[(size_t)z * 128 * CG + tid + k * 512];
  __syncthreads();
  int nl = tid & 63, oq = tid >> 6;  // oq in 0..7, wave-uniform
  int n = n0 + nl;
  float acc[16];
#pragma unroll
  for (int k = 0; k < 16; ++k) acc[k] = 0.f;
  const float* op = o_mid + (size_t)b * CG * N_ + n;
  for (int c = 0; c < CG; ++c) {
    float ov = op[(size_t)c * N_];
#pragma unroll
    for (int k = 0; k < 16; ++k) acc[k] += w_s[(oq * 16 + k) * CG + c] * ov;
  }
  float gm = gamma[0];
#pragma unroll
  for (int k = 0; k < 16; ++k) {
    int o = z * 128 + oq * 16 + k;
    size_t idx = ((size_t)b * C_ + o) * N_ + n;
    out[idx] = gm * acc[k] + x[idx];
  }
}

extern "C" void kernel_launch(void* const* d_in, const int* in_sizes, int n_in,
                              void* d_out, int out_size, void* d_ws, size_t ws_size,
                              hipStream_t stream) {
  const float* x = (const float*)d_in[0];
  const float* wt = (const float*)d_in[1];
  const float* wp = (const float*)d_in[2];
  const float* wg = (const float*)d_in[3];
  const float* wo = (const float*)d_in[4];
  const float* gamma = (const float*)d_in[5];
  float* out = (float*)d_out;

  float* theta = (float*)d_ws;                       // 8*32*4096   f32
  float* phi = theta + (size_t)B_ * CK * N_;         // 8*32*1024   f32
  float* g = phi + (size_t)B_ * CK * M_;             // 8*128*1024  f32
  float* o_mid = g + (size_t)B_ * CG * M_;           // 8*128*4096  f32

  theta_kernel<<<dim3(64, 8), 256, 0, stream>>>(x, wt, theta);
  pool_kernel<<<dim3(16, 8, 5), 256, 0, stream>>>(x, wp, wg, phi, g);
  attn_kernel<<<dim3(64, 8), 256, 0, stream>>>(theta, phi, g, o_mid);
  outproj_kernel<<<dim3(64, 8, 2), 512, 0, stream>>>(o_mid, wo, x, gamma, out);
}

// Round 4
// 68.287 us; speedup vs baseline: 7.3854x; 3.1597x over previous
//
#include <hip/hip_runtime.h>

#define B_ 8
#define C_ 256
#define N_ 4096
#define CK 32
#define CG 128
#define M_ 1024

typedef __attribute__((ext_vector_type(8))) short bf16x8;
typedef __attribute__((ext_vector_type(4))) float f32x4;

__device__ __forceinline__ short f2bf(float f) {
  union { float f; unsigned u; } v; v.f = f;
  unsigned r = (v.u + 0x7FFF + ((v.u >> 16) & 1)) >> 16;  // RNE
  return (short)r;
}
__device__ __forceinline__ int packbf2(float a, float b) {
  return (f2bf(a) & 0xFFFF) | (f2bf(b) << 16);
}

// ---------------- fused projection: theta (unpooled) + phi/g (2x2 maxpooled)
// All 192 output channels via bf16 MFMA. Block = 64 pixels (half of an image
// row-pair), pixel order nl = 2*xoff + dy so pool groups are 4 consecutive nl.
// Outputs (bf16): theta_t[b][n][32], phi_t[b][m][32], g_bf[b][c][m].
__global__ __launch_bounds__(512) void proj_kernel(const float* __restrict__ x,
                                                   const float* __restrict__ wt,
                                                   const float* __restrict__ wp,
                                                   const float* __restrict__ wg,
                                                   short* __restrict__ theta_t,
                                                   short* __restrict__ phi_t,
                                                   short* __restrict__ g_bf) {
  __shared__ __align__(16) short w_s[192 * 256];  // 96 KB, 16B-group swizzle g^(o&7)
  __shared__ __align__(16) short x_s[64 * 256];   // 32 KB, 16B-group swizzle g^(nl&7)
  int tid = threadIdx.x;
  int bx = blockIdx.x, b = blockIdx.y;
  int t = bx >> 1, half = bx & 1;

  // stage W: rows 0..31 theta, 32..63 phi, 64..191 g
#pragma unroll
  for (int rep = 0; rep < 12; ++rep) {
    int idx = rep * 512 + tid;
    int o = idx >> 5, gp = idx & 31;  // gp: 16B group (8 channels)
    const float* src = (o < 32) ? (wt + o * 256)
                     : (o < 64) ? (wp + (o - 32) * 256)
                                : (wg + (o - 64) * 256);
    float4 f0 = *(const float4*)(src + gp * 8);
    float4 f1 = *(const float4*)(src + gp * 8 + 4);
    int4 pk;
    pk.x = packbf2(f0.x, f0.y); pk.y = packbf2(f0.z, f0.w);
    pk.z = packbf2(f1.x, f1.y); pk.w = packbf2(f1.z, f1.w);
    *(int4*)&w_s[o * 256 + ((gp ^ (o & 7)) * 8)] = pk;
  }

  // stage x tile: 64 rows (nl) x 256 c, transpose+convert on the fly.
  {
    int l = tid & 63, cq = tid >> 6;  // cq 0..7
    int xoff = l >> 1, dy = l & 1;
    int n = t * 128 + dy * 64 + half * 32 + xoff;
    const float* xb = x + (size_t)b * C_ * N_ + n;
#pragma unroll
    for (int rep = 0; rep < 2; ++rep) {
      int ch = cq + rep * 8;  // 16-c chunk, 0..15
      int c0 = ch * 16;
      float f[16];
#pragma unroll
      for (int i = 0; i < 16; ++i) f[i] = xb[(size_t)(c0 + i) * N_];
      int4 pa, pb;
      pa.x = packbf2(f[0], f[1]);  pa.y = packbf2(f[2], f[3]);
      pa.z = packbf2(f[4], f[5]);  pa.w = packbf2(f[6], f[7]);
      pb.x = packbf2(f[8], f[9]);  pb.y = packbf2(f[10], f[11]);
      pb.z = packbf2(f[12], f[13]); pb.w = packbf2(f[14], f[15]);
      *(int4*)&x_s[l * 256 + (((2 * ch) ^ (l & 7)) * 8)] = pa;
      *(int4*)&x_s[l * 256 + (((2 * ch + 1) ^ (l & 7)) * 8)] = pb;
    }
  }
  __syncthreads();

  int lane = tid & 63, w = tid >> 6;
  int h = lane >> 4, q = lane & 15;
  int ns = w & 3, ow = w >> 2;  // wave: n-subtile ns, o-half ow
  f32x4 acc[6];
#pragma unroll
  for (int j = 0; j < 6; ++j) acc[j] = (f32x4){0.f, 0.f, 0.f, 0.f};

  int nl = 16 * ns + q;
#pragma unroll
  for (int ks = 0; ks < 8; ++ks) {
    bf16x8 bfr = *(const bf16x8*)&x_s[nl * 256 + (((4 * ks + h) ^ (nl & 7)) * 8)];
#pragma unroll
    for (int j = 0; j < 6; ++j) {
      int o = 16 * (6 * ow + j) + q;
      bf16x8 afr = *(const bf16x8*)&w_s[o * 256 + (((4 * ks + h) ^ (o & 7)) * 8)];
      acc[j] = __builtin_amdgcn_mfma_f32_16x16x32_bf16(afr, bfr, acc[j], 0, 0, 0);
    }
  }

  // epilogue: D[o = 16*ot+4h+r][col = nl]
  int xoff = nl >> 1, dy = nl & 1;
  int n = t * 128 + dy * 64 + half * 32 + xoff;
  int m = t * 32 + half * 16 + (nl >> 2);
#pragma unroll
  for (int j = 0; j < 6; ++j) {
    int ot = 6 * ow + j;
    if (ot < 2) {  // theta, unpooled
      int2 pp;
      pp.x = packbf2(acc[j][0], acc[j][1]);
      pp.y = packbf2(acc[j][2], acc[j][3]);
      *(int2*)&theta_t[((size_t)b * N_ + n) * CK + ot * 16 + 4 * h] = pp;
    } else {  // pooled: max over 4 consecutive nl lanes
      float v[4];
#pragma unroll
      for (int r = 0; r < 4; ++r) {
        float vv = acc[j][r];
        vv = fmaxf(vv, __shfl_xor(vv, 1));
        vv = fmaxf(vv, __shfl_xor(vv, 2));
        v[r] = vv;
      }
      if ((nl & 3) == 0) {
        if (ot < 4) {  // phi
          int2 pp;
          pp.x = packbf2(v[0], v[1]);
          pp.y = packbf2(v[2], v[3]);
          *(int2*)&phi_t[((size_t)b * M_ + m) * CK + (ot - 2) * 16 + 4 * h] = pp;
        } else {  // g
#pragma unroll
          for (int r = 0; r < 4; ++r) {
            int oc = (ot - 4) * 16 + 4 * h + r;
            g_bf[((size_t)b * CG + oc) * M_ + m] = f2bf(v[r]);
          }
        }
      }
    }
  }
}

// ---------------- fused flash attention with bf16 MFMA (bf16 in/out)
__global__ __launch_bounds__(256) void attn_kernel(const short* __restrict__ theta_t,
                                                   const short* __restrict__ phi_t,
                                                   const short* __restrict__ g_bf,
                                                   short* __restrict__ o_t) {
  __shared__ __align__(16) short phi_s[64 * 40];   // [m][c] stride 40
  __shared__ __align__(16) short g_s[128 * 72];    // [c][m] stride 72
  __shared__ __align__(16) short p_s[4][16 * 72];  // per-wave [q][m]

  int tid = threadIdx.x;
  int lane = tid & 63, w = tid >> 6;
  int h = lane >> 4, q = lane & 15;
  int b = blockIdx.y, n0 = blockIdx.x * 64;
  int n = n0 + 16 * w + q;

  bf16x8 qfrag = *(const bf16x8*)&theta_t[((size_t)b * N_ + n) * CK + 8 * h];

  f32x4 Oacc[8];
#pragma unroll
  for (int ct = 0; ct < 8; ++ct) Oacc[ct] = (f32x4){0.f, 0.f, 0.f, 0.f};
  float Mx = -INFINITY, S = 0.f;
  const f32x4 zero4 = {0.f, 0.f, 0.f, 0.f};

  for (int mt16 = 0; mt16 < 16; ++mt16) {
    int m0 = mt16 * 64;
    __syncthreads();
    {  // stage phi: [64 m][32 c] bf16
      int m = tid >> 2, cp = tid & 3;
      int4 v = *(const int4*)&phi_t[((size_t)b * M_ + m0 + m) * CK + 8 * cp];
      *(int4*)&phi_s[m * 40 + 8 * cp] = v;
    }
#pragma unroll
    for (int rep = 0; rep < 4; ++rep) {  // stage g: [128 c][64 m] bf16
      int idx = rep * 256 + tid;
      int c = idx >> 3, mc = idx & 7;
      int4 v = *(const int4*)&g_bf[((size_t)b * CG + c) * M_ + m0 + 8 * mc];
      *(int4*)&g_s[c * 72 + 8 * mc] = v;
    }
    __syncthreads();

    // QK^T: P^T[m][n]
    f32x4 pt[4];
#pragma unroll
    for (int mt = 0; mt < 4; ++mt) {
      bf16x8 af = *(const bf16x8*)&phi_s[(16 * mt + q) * 40 + 8 * h];
      pt[mt] = __builtin_amdgcn_mfma_f32_16x16x32_bf16(af, qfrag, zero4, 0, 0, 0);
    }

    float pm = pt[0][0];
#pragma unroll
    for (int mt = 0; mt < 4; ++mt)
#pragma unroll
      for (int r = 0; r < 4; ++r) pm = fmaxf(pm, pt[mt][r]);
    pm = fmaxf(pm, __shfl_xor(pm, 16));
    pm = fmaxf(pm, __shfl_xor(pm, 32));
    float Mn = fmaxf(Mx, pm);
    float fsc = __expf(Mx - Mn);
    float ps = 0.f;
#pragma unroll
    for (int mt = 0; mt < 4; ++mt) {
      float e0 = __expf(pt[mt][0] - Mn);
      float e1 = __expf(pt[mt][1] - Mn);
      float e2 = __expf(pt[mt][2] - Mn);
      float e3 = __expf(pt[mt][3] - Mn);
      ps += (e0 + e1) + (e2 + e3);
      int2 pk;
      pk.x = packbf2(e0, e1);
      pk.y = packbf2(e2, e3);
      *(int2*)&p_s[w][q * 72 + 16 * mt + 4 * h] = pk;
    }
    ps += __shfl_xor(ps, 16);
    ps += __shfl_xor(ps, 32);
    S = S * fsc + ps;
    Mx = Mn;
#pragma unroll
    for (int ct = 0; ct < 8; ++ct) Oacc[ct] *= fsc;

#pragma unroll
    for (int kp = 0; kp < 2; ++kp) {
      bf16x8 pf = *(const bf16x8*)&p_s[w][q * 72 + 32 * kp + 8 * h];
#pragma unroll
      for (int ct = 0; ct < 8; ++ct) {
        bf16x8 vf = *(const bf16x8*)&g_s[(16 * ct + q) * 72 + 32 * kp + 8 * h];
        Oacc[ct] = __builtin_amdgcn_mfma_f32_16x16x32_bf16(vf, pf, Oacc[ct], 0, 0, 0);
      }
    }
  }

  // epilogue: o_t[b][n][c] bf16
  float rS = 1.f / S;
#pragma unroll
  for (int ct = 0; ct < 8; ++ct) {
    int2 pp;
    pp.x = packbf2(Oacc[ct][0] * rS, Oacc[ct][1] * rS);
    pp.y = packbf2(Oacc[ct][2] * rS, Oacc[ct][3] * rS);
    *(int2*)&o_t[((size_t)b * N_ + n) * CG + 16 * ct + 4 * h] = pp;
  }
}

// ---------------- out projection + residual via bf16 MFMA
// Block tile: 256 o x 64 n. 8 waves = 4 n-subtiles x 2 o-halves (o-half = 128
// channels = 8 MFMA o-tiles per wave).
__global__ __launch_bounds__(512) void outproj_kernel(const short* __restrict__ o_t,
                                                      const float* __restrict__ wo,
                                                      const float* __restrict__ x,
                                                      const float* __restrict__ gamma,
                                                      float* __restrict__ out) {
  __shared__ __align__(16) short wo_s[256 * 128];  // 64 KB, swizzle g^(o&7)
  __shared__ __align__(16) short ot_s[64 * 128];   // 16 KB, swizzle g^(n&7)
  int tid = threadIdx.x;
  int b = blockIdx.y, n0 = blockIdx.x * 64;

#pragma unroll
  for (int rep = 0; rep < 8; ++rep) {  // stage wo: [256 o][128 c] f32 -> bf16
    int idx = rep * 512 + tid;
    int o = idx >> 4, gp = idx & 15;
    float4 f0 = *(const float4*)(wo + o * 128 + gp * 8);
    float4 f1 = *(const float4*)(wo + o * 128 + gp * 8 + 4);
    int4 pk;
    pk.x = packbf2(f0.x, f0.y); pk.y = packbf2(f0.z, f0.w);
    pk.z = packbf2(f1.x, f1.y); pk.w = packbf2(f1.z, f1.w);
    *(int4*)&wo_s[o * 128 + ((gp ^ (o & 7)) * 8)] = pk;
  }
#pragma unroll
  for (int rep = 0; rep < 2; ++rep) {  // stage o_t tile: [64 n][128 c]
    int idx = rep * 512 + tid;
    int nl = idx >> 4, gp = idx & 15;
    int4 v = *(const int4*)&o_t[((size_t)b * N_ + n0 + nl) * CG + 8 * gp];
    *(int4*)&ot_s[nl * 128 + ((gp ^ (nl & 7)) * 8)] = v;
  }
  __syncthreads();

  int lane = tid & 63, w = tid >> 6;
  int h = lane >> 4, q = lane & 15;
  int ns = w & 3, oh = w >> 2;
  f32x4 acc[8];
#pragma unroll
  for (int j = 0; j < 8; ++j) acc[j] = (f32x4){0.f, 0.f, 0.f, 0.f};

  int nl = 16 * ns + q;
#pragma unroll
  for (int ks = 0; ks < 4; ++ks) {
    bf16x8 bfr = *(const bf16x8*)&ot_s[nl * 128 + (((4 * ks + h) ^ (nl & 7)) * 8)];
#pragma unroll
    for (int j = 0; j < 8; ++j) {
      int o = 128 * oh + 16 * j + q;
      bf16x8 afr = *(const bf16x8*)&wo_s[o * 128 + (((4 * ks + h) ^ (o & 7)) * 8)];
      acc[j] = __builtin_amdgcn_mfma_f32_16x16x32_bf16(afr, bfr, acc[j], 0, 0, 0);
    }
  }

  float gm = gamma[0];
  int n = n0 + 16 * ns + q;
#pragma unroll
  for (int j = 0; j < 8; ++j)
#pragma unroll
    for (int r = 0; r < 4; ++r) {
      int o = 128 * oh + 16 * j + 4 * h + r;
      size_t idx = ((size_t)b * C_ + o) * N_ + n;
      out[idx] = gm * acc[j][r] + x[idx];
    }
}

extern "C" void kernel_launch(void* const* d_in, const int* in_sizes, int n_in,
                              void* d_out, int out_size, void* d_ws, size_t ws_size,
                              hipStream_t stream) {
  const float* x = (const float*)d_in[0];
  const float* wt = (const float*)d_in[1];
  const float* wp = (const float*)d_in[2];
  const float* wg = (const float*)d_in[3];
  const float* wo = (const float*)d_in[4];
  const float* gamma = (const float*)d_in[5];
  float* out = (float*)d_out;

  short* theta_t = (short*)d_ws;                       // 8*4096*32  sh
  short* phi_t = theta_t + (size_t)B_ * N_ * CK;       // 8*1024*32  sh
  short* g_bf = phi_t + (size_t)B_ * M_ * CK;          // 8*128*1024 sh
  short* o_t = g_bf + (size_t)B_ * CG * M_;            // 8*4096*128 sh

  proj_kernel<<<dim3(64, 8), 512, 0, stream>>>(x, wt, wp, wg, theta_t, phi_t, g_bf);
  attn_kernel<<<dim3(64, 8), 256, 0, stream>>>(theta_t, phi_t, g_bf, o_t);
  outproj_kernel<<<dim3(64, 8), 512, 0, stream>>>(o_t, wo, x, gamma, out);
}

// Round 5
// 65.870 us; speedup vs baseline: 7.6564x; 1.0367x over previous
//
#include <hip/hip_runtime.h>

#define B_ 8
#define C_ 256
#define N_ 4096
#define CK 32
#define CG 128
#define M_ 1024

typedef __attribute__((ext_vector_type(8))) short bf16x8;
typedef __attribute__((ext_vector_type(4))) float f32x4;

__device__ __forceinline__ short f2bf(float f) {
  union { float f; unsigned u; } v; v.f = f;
  unsigned r = (v.u + 0x7FFF + ((v.u >> 16) & 1)) >> 16;  // RNE
  return (short)r;
}
__device__ __forceinline__ int packbf2(float a, float b) {
  return (f2bf(a) & 0xFFFF) | (f2bf(b) << 16);
}
__device__ __forceinline__ int cvtpk(float lo, float hi) {
  int r;
  asm("v_cvt_pk_bf16_f32 %0, %1, %2" : "=v"(r) : "v"(lo), "v"(hi));
  return r;
}

// ---------------- weight pre-convert: f32 -> bf16, once per launch
// wcat = concat(wt[32x256], wp[32x256], wg[128x256]); wo_bf = wo[256x128]
__global__ __launch_bounds__(256) void prep_kernel(const float* __restrict__ wt,
                                                   const float* __restrict__ wp,
                                                   const float* __restrict__ wg,
                                                   const float* __restrict__ wo,
                                                   short* __restrict__ wcat,
                                                   short* __restrict__ wo_bf) {
  int i = (blockIdx.x * 256 + threadIdx.x) * 4;
  const float* src;
  short* dst;
  int off;
  if (i < 8192)        { src = wt; dst = wcat;         off = i; }
  else if (i < 16384)  { src = wp; dst = wcat + 8192;  off = i - 8192; }
  else if (i < 49152)  { src = wg; dst = wcat + 16384; off = i - 16384; }
  else                 { src = wo; dst = wo_bf;        off = i - 49152; }
  float4 v = *(const float4*)(src + off);
  int2 p;
  p.x = packbf2(v.x, v.y);
  p.y = packbf2(v.z, v.w);
  *(int2*)(dst + off) = p;
}

// ---------------- fused projection: theta (unpooled) + phi/g (2x2 maxpooled)
__global__ __launch_bounds__(512) void proj_kernel(const float* __restrict__ x,
                                                   const short* __restrict__ wcat,
                                                   short* __restrict__ theta_t,
                                                   short* __restrict__ phi_t,
                                                   short* __restrict__ g_bf) {
  __shared__ __align__(16) short w_s[192 * 256];  // 96 KB, 16B-group swizzle g^(o&7)
  __shared__ __align__(16) short x_s[64 * 256];   // 32 KB, 16B-group swizzle g^(nl&7)
  int tid = threadIdx.x;
  int bx = blockIdx.x, b = blockIdx.y;
  int t = bx >> 1, half = bx & 1;

  // stage W (already bf16): rows 0..31 theta, 32..63 phi, 64..191 g
#pragma unroll
  for (int rep = 0; rep < 12; ++rep) {
    int idx = rep * 512 + tid;
    int o = idx >> 5, gp = idx & 31;  // gp: 16B group (8 channels)
    int4 v = *(const int4*)&wcat[o * 256 + gp * 8];
    *(int4*)&w_s[o * 256 + ((gp ^ (o & 7)) * 8)] = v;
  }

  // stage x tile: 64 rows (nl) x 256 c, transpose+convert on the fly.
  {
    int l = tid & 63, cq = tid >> 6;  // cq 0..7
    int xoff = l >> 1, dy = l & 1;
    int n = t * 128 + dy * 64 + half * 32 + xoff;
    const float* xb = x + (size_t)b * C_ * N_ + n;
#pragma unroll
    for (int rep = 0; rep < 2; ++rep) {
      int ch = cq + rep * 8;  // 16-c chunk, 0..15
      int c0 = ch * 16;
      float f[16];
#pragma unroll
      for (int i = 0; i < 16; ++i) f[i] = xb[(size_t)(c0 + i) * N_];
      int4 pa, pb;
      pa.x = cvtpk(f[0], f[1]);   pa.y = cvtpk(f[2], f[3]);
      pa.z = cvtpk(f[4], f[5]);   pa.w = cvtpk(f[6], f[7]);
      pb.x = cvtpk(f[8], f[9]);   pb.y = cvtpk(f[10], f[11]);
      pb.z = cvtpk(f[12], f[13]); pb.w = cvtpk(f[14], f[15]);
      *(int4*)&x_s[l * 256 + (((2 * ch) ^ (l & 7)) * 8)] = pa;
      *(int4*)&x_s[l * 256 + (((2 * ch + 1) ^ (l & 7)) * 8)] = pb;
    }
  }
  __syncthreads();

  int lane = tid & 63, w = tid >> 6;
  int h = lane >> 4, q = lane & 15;
  int ns = w & 3, ow = w >> 2;  // wave: n-subtile ns, o-half ow
  f32x4 acc[6];
#pragma unroll
  for (int j = 0; j < 6; ++j) acc[j] = (f32x4){0.f, 0.f, 0.f, 0.f};

  int nl = 16 * ns + q;
#pragma unroll
  for (int ks = 0; ks < 8; ++ks) {
    bf16x8 bfr = *(const bf16x8*)&x_s[nl * 256 + (((4 * ks + h) ^ (nl & 7)) * 8)];
#pragma unroll
    for (int j = 0; j < 6; ++j) {
      int o = 16 * (6 * ow + j) + q;
      bf16x8 afr = *(const bf16x8*)&w_s[o * 256 + (((4 * ks + h) ^ (o & 7)) * 8)];
      acc[j] = __builtin_amdgcn_mfma_f32_16x16x32_bf16(afr, bfr, acc[j], 0, 0, 0);
    }
  }

  // epilogue: D[o = 16*ot+4h+r][col = nl]
  int xoff = nl >> 1, dy = nl & 1;
  int n = t * 128 + dy * 64 + half * 32 + xoff;
  int m = t * 32 + half * 16 + (nl >> 2);
#pragma unroll
  for (int j = 0; j < 6; ++j) {
    int ot = 6 * ow + j;
    if (ot < 2) {  // theta, unpooled
      int2 pp;
      pp.x = cvtpk(acc[j][0], acc[j][1]);
      pp.y = cvtpk(acc[j][2], acc[j][3]);
      *(int2*)&theta_t[((size_t)b * N_ + n) * CK + ot * 16 + 4 * h] = pp;
    } else {  // pooled: max over 4 consecutive nl lanes
      float v[4];
#pragma unroll
      for (int r = 0; r < 4; ++r) {
        float vv = acc[j][r];
        vv = fmaxf(vv, __shfl_xor(vv, 1));
        vv = fmaxf(vv, __shfl_xor(vv, 2));
        v[r] = vv;
      }
      if ((nl & 3) == 0) {
        if (ot < 4) {  // phi
          int2 pp;
          pp.x = cvtpk(v[0], v[1]);
          pp.y = cvtpk(v[2], v[3]);
          *(int2*)&phi_t[((size_t)b * M_ + m) * CK + (ot - 2) * 16 + 4 * h] = pp;
        } else {  // g
#pragma unroll
          for (int r = 0; r < 4; ++r) {
            int oc = (ot - 4) * 16 + 4 * h + r;
            g_bf[((size_t)b * CG + oc) * M_ + m] = f2bf(v[r]);
          }
        }
      }
    }
  }
}

// ---------------- fused flash attention, bf16 MFMA, async-stage + defer-max
__global__ __launch_bounds__(256) void attn_kernel(const short* __restrict__ theta_t,
                                                   const short* __restrict__ phi_t,
                                                   const short* __restrict__ g_bf,
                                                   short* __restrict__ o_t) {
  __shared__ __align__(16) short phi_s[64 * 40];   // [m][c] stride 40
  __shared__ __align__(16) short g_s[128 * 72];    // [c][m] stride 72
  __shared__ __align__(16) short p_s[4][16 * 72];  // per-wave [q][m]

  int tid = threadIdx.x;
  int lane = tid & 63, w = tid >> 6;
  int h = lane >> 4, q = lane & 15;
  int b = blockIdx.y, n0 = blockIdx.x * 64;
  int n = n0 + 16 * w + q;

  bf16x8 qfrag = *(const bf16x8*)&theta_t[((size_t)b * N_ + n) * CK + 8 * h];

  f32x4 Oacc[8];
#pragma unroll
  for (int ct = 0; ct < 8; ++ct) Oacc[ct] = (f32x4){0.f, 0.f, 0.f, 0.f};
  float Mx = -INFINITY, S = 0.f;
  const f32x4 zero4 = {0.f, 0.f, 0.f, 0.f};

  int mp = tid >> 2, cpp = tid & 3;  // phi staging coords

  // prologue: stage tile 0 directly
  {
    int4 v = *(const int4*)&phi_t[((size_t)b * M_ + mp) * CK + 8 * cpp];
    *(int4*)&phi_s[mp * 40 + 8 * cpp] = v;
#pragma unroll
    for (int rep = 0; rep < 4; ++rep) {
      int idx = rep * 256 + tid;
      int c = idx >> 3, mc = idx & 7;
      int4 v2 = *(const int4*)&g_bf[((size_t)b * CG + c) * M_ + 8 * mc];
      *(int4*)&g_s[c * 72 + 8 * mc] = v2;
    }
  }
  __syncthreads();

  for (int mt16 = 0; mt16 < 16; ++mt16) {
    // issue next tile's global loads early (latency hides under compute)
    int4 rphi, rg0, rg1, rg2, rg3;
    if (mt16 < 15) {
      int m0n = (mt16 + 1) * 64;
      rphi = *(const int4*)&phi_t[((size_t)b * M_ + m0n + mp) * CK + 8 * cpp];
      {
        int idx = tid;           int c = idx >> 3, mc = idx & 7;
        rg0 = *(const int4*)&g_bf[((size_t)b * CG + c) * M_ + m0n + 8 * mc];
      }
      { int idx = 256 + tid;     int c = idx >> 3, mc = idx & 7;
        rg1 = *(const int4*)&g_bf[((size_t)b * CG + c) * M_ + m0n + 8 * mc]; }
      { int idx = 512 + tid;     int c = idx >> 3, mc = idx & 7;
        rg2 = *(const int4*)&g_bf[((size_t)b * CG + c) * M_ + m0n + 8 * mc]; }
      { int idx = 768 + tid;     int c = idx >> 3, mc = idx & 7;
        rg3 = *(const int4*)&g_bf[((size_t)b * CG + c) * M_ + m0n + 8 * mc]; }
    }

    // QK^T: P^T[m][n]
    f32x4 pt[4];
#pragma unroll
    for (int mt = 0; mt < 4; ++mt) {
      bf16x8 af = *(const bf16x8*)&phi_s[(16 * mt + q) * 40 + 8 * h];
      pt[mt] = __builtin_amdgcn_mfma_f32_16x16x32_bf16(af, qfrag, zero4, 0, 0, 0);
    }

    // online softmax with defer-max (THR=8)
    float pm = pt[0][0];
#pragma unroll
    for (int mt = 0; mt < 4; ++mt)
#pragma unroll
      for (int r = 0; r < 4; ++r) pm = fmaxf(pm, pt[mt][r]);
    pm = fmaxf(pm, __shfl_xor(pm, 16));
    pm = fmaxf(pm, __shfl_xor(pm, 32));
    if (!__all(pm - Mx <= 8.f)) {
      float Mn = fmaxf(Mx, pm);
      float fsc = __expf(Mx - Mn);
      S *= fsc;
#pragma unroll
      for (int ct = 0; ct < 8; ++ct) Oacc[ct] *= fsc;
      Mx = Mn;
    }
    float ps = 0.f;
#pragma unroll
    for (int mt = 0; mt < 4; ++mt) {
      float e0 = __expf(pt[mt][0] - Mx);
      float e1 = __expf(pt[mt][1] - Mx);
      float e2 = __expf(pt[mt][2] - Mx);
      float e3 = __expf(pt[mt][3] - Mx);
      ps += (e0 + e1) + (e2 + e3);
      int2 pk;
      pk.x = cvtpk(e0, e1);
      pk.y = cvtpk(e2, e3);
      *(int2*)&p_s[w][q * 72 + 16 * mt + 4 * h] = pk;
    }
    ps += __shfl_xor(ps, 16);
    ps += __shfl_xor(ps, 32);
    S += ps;

    // PV
#pragma unroll
    for (int kp = 0; kp < 2; ++kp) {
      bf16x8 pf = *(const bf16x8*)&p_s[w][q * 72 + 32 * kp + 8 * h];
#pragma unroll
      for (int ct = 0; ct < 8; ++ct) {
        bf16x8 vf = *(const bf16x8*)&g_s[(16 * ct + q) * 72 + 32 * kp + 8 * h];
        Oacc[ct] = __builtin_amdgcn_mfma_f32_16x16x32_bf16(vf, pf, Oacc[ct], 0, 0, 0);
      }
    }

    __syncthreads();  // all reads of phi_s/g_s done
    if (mt16 < 15) {
      *(int4*)&phi_s[mp * 40 + 8 * cpp] = rphi;
      { int idx = tid;       int c = idx >> 3, mc = idx & 7; *(int4*)&g_s[c * 72 + 8 * mc] = rg0; }
      { int idx = 256 + tid; int c = idx >> 3, mc = idx & 7; *(int4*)&g_s[c * 72 + 8 * mc] = rg1; }
      { int idx = 512 + tid; int c = idx >> 3, mc = idx & 7; *(int4*)&g_s[c * 72 + 8 * mc] = rg2; }
      { int idx = 768 + tid; int c = idx >> 3, mc = idx & 7; *(int4*)&g_s[c * 72 + 8 * mc] = rg3; }
      __syncthreads();  // staged writes visible
    }
  }

  // epilogue: o_t[b][n][c] bf16
  float rS = 1.f / S;
#pragma unroll
  for (int ct = 0; ct < 8; ++ct) {
    int2 pp;
    pp.x = cvtpk(Oacc[ct][0] * rS, Oacc[ct][1] * rS);
    pp.y = cvtpk(Oacc[ct][2] * rS, Oacc[ct][3] * rS);
    *(int2*)&o_t[((size_t)b * N_ + n) * CG + 16 * ct + 4 * h] = pp;
  }
}

// ---------------- out projection + residual via bf16 MFMA (256 o x 64 n tile)
__global__ __launch_bounds__(512) void outproj_kernel(const short* __restrict__ o_t,
                                                      const short* __restrict__ wo_bf,
                                                      const float* __restrict__ x,
                                                      const float* __restrict__ gamma,
                                                      float* __restrict__ out) {
  __shared__ __align__(16) short wo_s[256 * 128];  // 64 KB, swizzle g^(o&7)
  __shared__ __align__(16) short ot_s[64 * 128];   // 16 KB, swizzle g^(n&7)
  int tid = threadIdx.x;
  int b = blockIdx.y, n0 = blockIdx.x * 64;

#pragma unroll
  for (int rep = 0; rep < 8; ++rep) {  // stage wo (bf16): [256 o][128 c]
    int idx = rep * 512 + tid;
    int o = idx >> 4, gp = idx & 15;
    int4 v = *(const int4*)&wo_bf[o * 128 + gp * 8];
    *(int4*)&wo_s[o * 128 + ((gp ^ (o & 7)) * 8)] = v;
  }
#pragma unroll
  for (int rep = 0; rep < 2; ++rep) {  // stage o_t tile: [64 n][128 c]
    int idx = rep * 512 + tid;
    int nl = idx >> 4, gp = idx & 15;
    int4 v = *(const int4*)&o_t[((size_t)b * N_ + n0 + nl) * CG + 8 * gp];
    *(int4*)&ot_s[nl * 128 + ((gp ^ (nl & 7)) * 8)] = v;
  }
  __syncthreads();

  int lane = tid & 63, w = tid >> 6;
  int h = lane >> 4, q = lane & 15;
  int ns = w & 3, oh = w >> 2;
  f32x4 acc[8];
#pragma unroll
  for (int j = 0; j < 8; ++j) acc[j] = (f32x4){0.f, 0.f, 0.f, 0.f};

  int nl = 16 * ns + q;
#pragma unroll
  for (int ks = 0; ks < 4; ++ks) {
    bf16x8 bfr = *(const bf16x8*)&ot_s[nl * 128 + (((4 * ks + h) ^ (nl & 7)) * 8)];
#pragma unroll
    for (int j = 0; j < 8; ++j) {
      int o = 128 * oh + 16 * j + q;
      bf16x8 afr = *(const bf16x8*)&wo_s[o * 128 + (((4 * ks + h) ^ (o & 7)) * 8)];
      acc[j] = __builtin_amdgcn_mfma_f32_16x16x32_bf16(afr, bfr, acc[j], 0, 0, 0);
    }
  }

  float gm = gamma[0];
  int n = n0 + 16 * ns + q;
#pragma unroll
  for (int j = 0; j < 8; ++j)
#pragma unroll
    for (int r = 0; r < 4; ++r) {
      int o = 128 * oh + 16 * j + 4 * h + r;
      size_t idx = ((size_t)b * C_ + o) * N_ + n;
      out[idx] = gm * acc[j][r] + x[idx];
    }
}

extern "C" void kernel_launch(void* const* d_in, const int* in_sizes, int n_in,
                              void* d_out, int out_size, void* d_ws, size_t ws_size,
                              hipStream_t stream) {
  const float* x = (const float*)d_in[0];
  const float* wt = (const float*)d_in[1];
  const float* wp = (const float*)d_in[2];
  const float* wg = (const float*)d_in[3];
  const float* wo = (const float*)d_in[4];
  const float* gamma = (const float*)d_in[5];
  float* out = (float*)d_out;

  short* theta_t = (short*)d_ws;                       // 8*4096*32
  short* phi_t = theta_t + (size_t)B_ * N_ * CK;       // 8*1024*32
  short* g_bf = phi_t + (size_t)B_ * M_ * CK;          // 8*128*1024
  short* o_t = g_bf + (size_t)B_ * CG * M_;            // 8*4096*128
  short* wcat = o_t + (size_t)B_ * N_ * CG;            // 192*256
  short* wo_bf = wcat + 192 * 256;                     // 256*128

  prep_kernel<<<dim3(80), 256, 0, stream>>>(wt, wp, wg, wo, wcat, wo_bf);
  proj_kernel<<<dim3(64, 8), 512, 0, stream>>>(x, wcat, theta_t, phi_t, g_bf);
  attn_kernel<<<dim3(64, 8), 256, 0, stream>>>(theta_t, phi_t, g_bf, o_t);
  outproj_kernel<<<dim3(64, 8), 512, 0, stream>>>(o_t, wo_bf, x, gamma, out);
}